// Round 4
// baseline (317.192 us; speedup 1.0000x reference)
//
#include <hip/hip_runtime.h>
#include <hip/hip_bf16.h>

// Problem constants (B,T,H fixed by setup_inputs)
#define B_ 16
#define T_ 8192
#define H_ 256
#define M_ (B_ * T_)   // 131072 rows
#define STRIDE_ 8      // window over [max(0,t-8), t], count = min(t+1, 9)

typedef __bf16 bf16x8 __attribute__((ext_vector_type(8)));
typedef float f32x4 __attribute__((ext_vector_type(4)));

// round-to-nearest-even fp32 -> bf16 bits
__device__ __forceinline__ unsigned short f2bf(float f) {
  unsigned u = __builtin_bit_cast(unsigned, f);
  u += 0x7fffu + ((u >> 16) & 1u);
  return (unsigned short)(u >> 16);
}

// ---------------------------------------------------------------------------
// Kernel 1: Wpk[ks][n][kk] = bf16(Wcat[n][ks*32+kk]), ks<16, n<256, kk<32
//   Wcat[n][k] = k<256 ? W_lin[n][k] : W_mem[n][k-256]
// Laid out so a wave's b-frag load (16 rows x 16B at fixed kq) is one
// coalesced 1 KB segment. Also bias[o] = b_lin[o]+b_mem[o].
// ---------------------------------------------------------------------------
__global__ __launch_bounds__(256) void wcat_kernel(
    const float* __restrict__ Wl, const float* __restrict__ bl,
    const float* __restrict__ Wm, const float* __restrict__ bm,
    unsigned short* __restrict__ Wpk, float* __restrict__ bias) {
  const int e = blockIdx.x * 256 + threadIdx.x;
  const int ks = e >> 13;
  const int n = (e >> 5) & 255;
  const int kk = e & 31;
  const int k = ks * 32 + kk;
  const float w = (k < 256) ? Wl[n * 256 + k] : Wm[n * 256 + (k - 256)];
  Wpk[e] = f2bf(w);
  if (e < 256) bias[e] = bl[e] + bm[e];
}

// ---------------------------------------------------------------------------
// Kernel 2 (fused): out[M,256] = [x | winmean(x)] @ Wcat^T + bias
// Block: 64 rows x 256 cols, 256 threads = 4 waves (each 64x64, wc=w*64).
// 8 iterations; iter it covers K-steps {it} (x cols) and {it+8} (mean cols).
//  - A: x chunk read once -> regs -> means via running sum -> ds_write into
//    XOR-swizzled As[it&1]  (double buffer -> ONE barrier per iter)
//  - B: direct global->reg b-frags from Wpk (L2-resident, no LDS, no drain)
//  - x for it+1 prefetched into regs during the MFMA phase
// grid: 2048 x 256
// ---------------------------------------------------------------------------
__global__ __launch_bounds__(256, 3) void fused_kernel(
    const float* __restrict__ x,            // [M, 256] fp32
    const unsigned short* __restrict__ Wpk, // [16][256][32] bf16 bits
    const float* __restrict__ bias,         // [256]
    float* __restrict__ out) {              // [M, 256] fp32
  __shared__ __align__(16) unsigned short As[2][64 * 64];  // 16 KB total
  const int tid = threadIdx.x;
  const int m0 = blockIdx.x << 6;
  const int tb0 = m0 & (T_ - 1);   // token of tile row 0 within its batch
  const int w = tid >> 6;
  const int l = tid & 63;
  const int wc = w << 6;           // wave N offset
  const int lm = l & 15;
  const int kc4 = l >> 4;          // 16B-chunk index within 32 elems (0..3)
  const int kq = kc4 << 3;         // element offset within 32

  // A staging: col-pair p (16 float2 pairs of the 32-col chunk),
  //            row-group g (16 groups x 4 rows)
  const int p = tid & 15, g = tid >> 4;
  const float2* __restrict__ x2 = (const float2*)x;

  f32x4 acc[4][4];
#pragma unroll
  for (int i = 0; i < 4; ++i)
#pragma unroll
    for (int j = 0; j < 4; ++j) acc[i][j] = (f32x4){0.f, 0.f, 0.f, 0.f};

  // prologue: load x chunk for it=0 (8-row halo above group)
  float2 v[12];
#pragma unroll
  for (int i = 0; i < 12; ++i) {
    const int rl = (g << 2) - 8 + i;
    float2 val = {0.f, 0.f};
    if (tb0 + rl >= 0) val = x2[(size_t)(m0 + rl) * 128 + p];
    v[i] = val;
  }

  for (int it = 0; it < 8; ++it) {
    const int cur = it & 1;
    unsigned* __restrict__ As32 = (unsigned*)As[cur];

    // --- means (running 9-row window) + swizzled ds_write ---
    float sx = 0.f, sy = 0.f;
#pragma unroll
    for (int i = 0; i < 8; ++i) { sx += v[i].x; sy += v[i].y; }
#pragma unroll
    for (int rr = 0; rr < 4; ++rr) {
      sx += v[rr + 8].x; sy += v[rr + 8].y;
      const int r = (g << 2) + rr;
      const int t = tb0 + r;
      const float inv =
          (t >= STRIDE_) ? (1.f / 9.f) : __builtin_amdgcn_rcpf((float)(t + 1));
      const unsigned xp =
          (unsigned)f2bf(v[rr + 8].x) | ((unsigned)f2bf(v[rr + 8].y) << 16);
      const unsigned mp =
          (unsigned)f2bf(sx * inv) | ((unsigned)f2bf(sy * inv) << 16);
      const int sw = r & 7;
      As32[r * 32 + (((p >> 2) ^ sw) << 2) + (p & 3)] = xp;        // chunks 0-3
      As32[r * 32 + (((4 + (p >> 2)) ^ sw) << 2) + (p & 3)] = mp;  // chunks 4-7
      sx -= v[rr].x; sy -= v[rr].y;
    }
    __syncthreads();  // As[cur] visible; drains prefetched x (vmcnt) + lgkm

    // --- B: direct global->reg b-frags (k-steps it and it+8) ---
    const size_t bb0 = ((size_t)it << 13) + (wc + lm) * 32 + kq;
    const size_t bb1 = bb0 + ((size_t)8 << 13);
    bf16x8 b0[4], b1[4], a0[4], a1[4];
#pragma unroll
    for (int j = 0; j < 4; ++j) b0[j] = *(const bf16x8*)&Wpk[bb0 + (j << 9)];
#pragma unroll
    for (int j = 0; j < 4; ++j) b1[j] = *(const bf16x8*)&Wpk[bb1 + (j << 9)];
    // --- A: swizzled ds_read_b128 frags ---
#pragma unroll
    for (int i = 0; i < 4; ++i) {
      const int R = (i << 4) + lm;
      a0[i] = *(const bf16x8*)&As[cur][R * 64 + ((kc4 ^ (R & 7)) << 3)];
      a1[i] = *(const bf16x8*)&As[cur][R * 64 + (((4 + kc4) ^ (R & 7)) << 3)];
    }
    // --- x prefetch for it+1 (latency hides behind MFMAs + next barrier) ---
    if (it < 7) {
#pragma unroll
      for (int i = 0; i < 12; ++i) {
        const int rl = (g << 2) - 8 + i;
        float2 val = {0.f, 0.f};
        if (tb0 + rl >= 0)
          val = x2[(size_t)(m0 + rl) * 128 + ((it + 1) << 4) + p];
        v[i] = val;
      }
    }
    // --- MFMA: 2 k-steps x 16 ---
#pragma unroll
    for (int i = 0; i < 4; ++i)
#pragma unroll
      for (int j = 0; j < 4; ++j)
        acc[i][j] =
            __builtin_amdgcn_mfma_f32_16x16x32_bf16(a0[i], b0[j], acc[i][j], 0, 0, 0);
#pragma unroll
    for (int i = 0; i < 4; ++i)
#pragma unroll
      for (int j = 0; j < 4; ++j)
        acc[i][j] =
            __builtin_amdgcn_mfma_f32_16x16x32_bf16(a1[i], b1[j], acc[i][j], 0, 0, 0);
  }

  // epilogue: C/D layout col = l&15, row = (l>>4)*4 + reg
  const int r0 = (l >> 4) << 2;
#pragma unroll
  for (int j = 0; j < 4; ++j) {
    const int o = wc + (j << 4) + lm;
    const float bs = bias[o];
#pragma unroll
    for (int i = 0; i < 4; ++i) {
      const size_t mr = (size_t)(m0 + (i << 4) + r0);
#pragma unroll
      for (int r = 0; r < 4; ++r) out[(mr + r) * 256 + o] = acc[i][j][r] + bs;
    }
  }
}

// ---------------------------------------------------------------------------
extern "C" void kernel_launch(void* const* d_in, const int* in_sizes, int n_in,
                              void* d_out, int out_size, void* d_ws, size_t ws_size,
                              hipStream_t stream) {
  const float* x  = (const float*)d_in[0];
  const float* Wl = (const float*)d_in[1];
  const float* bl = (const float*)d_in[2];
  const float* Wm = (const float*)d_in[3];
  const float* bm = (const float*)d_in[4];
  float* out = (float*)d_out;

  // workspace: Wpk 16x256x32 bf16 (256 KiB) + bias 256 f32 (1 KiB)
  char* ws = (char*)d_ws;
  unsigned short* Wpk = (unsigned short*)ws;
  float* bias = (float*)(ws + (size_t)16 * 256 * 32 * 2);

  wcat_kernel<<<512, 256, 0, stream>>>(Wl, bl, Wm, bm, Wpk, bias);
  fused_kernel<<<2048, 256, 0, stream>>>(x, Wpk, bias, out);
}